// Round 1
// baseline (6251.334 us; speedup 1.0000x reference)
//
#include <hip/hip_runtime.h>
#include <hip/hip_bf16.h>
#include <cstdint>

#define S_LEN 1024
#define HID   4096
#define NH    32
#define NKV   8
#define HD    128
#define NLOW  3968      // HID - SEL
#define M_ROWS 2048     // B*S
#define NQKV  6144      // (NH+2*NKV)*HD

// ---------- wave/block reductions ----------
__device__ inline float wred_max(float v){ for(int o=32;o;o>>=1) v=fmaxf(v,__shfl_xor(v,o)); return v; }
__device__ inline float wred_min(float v){ for(int o=32;o;o>>=1) v=fminf(v,__shfl_xor(v,o)); return v; }
__device__ inline float wred_sum(float v){ for(int o=32;o;o>>=1) v+=__shfl_xor(v,o); return v; }

__device__ inline float bsum128(float v, float* red, int t){
  v = wred_sum(v);
  if ((t&63)==0) red[t>>6] = v;
  __syncthreads();
  float r = red[0] + red[1];
  __syncthreads();
  return r;
}
__device__ inline float bmax128(float v, float* red, int t){
  v = wred_max(v);
  if ((t&63)==0) red[t>>6] = v;
  __syncthreads();
  float r = fmaxf(red[0], red[1]);
  __syncthreads();
  return r;
}
__device__ inline float bmin128(float v, float* red, int t){
  v = wred_min(v);
  if ((t&63)==0) red[t>>6] = v;
  __syncthreads();
  float r = fminf(red[0], red[1]);
  __syncthreads();
  return r;
}

// ---------- 1. activation permute + per-row int8 quant (first NLOW cols) ----------
__global__ __launch_bounds__(256) void aquant_kernel(const float* __restrict__ X,
                                                     const int* __restrict__ reorder,
                                                     float* __restrict__ out)
{
  __shared__ float xs[HID];
  __shared__ float red[256];
  int row = blockIdx.x;
  int t = threadIdx.x;
  const float* xr = X + (size_t)row * HID;
  float amax = 0.f;
  for (int c = t; c < HID; c += 256) {
    float v = xr[reorder[c]];
    xs[c] = v;
    if (c < NLOW) amax = fmaxf(amax, fabsf(v));
  }
  red[t] = amax;
  __syncthreads();
  for (int s = 128; s > 0; s >>= 1) {
    if (t < s) red[t] = fmaxf(red[t], red[t + s]);
    __syncthreads();
  }
  float scale = fmaxf(red[0], 1e-5f) / 127.0f;
  float* orow = out + (size_t)row * HID;
  for (int c = t; c < HID; c += 256) {
    float v = xs[c];
    if (c < NLOW) {
      float q = fminf(fmaxf(rintf(v / scale), -128.f), 127.f);
      v = q * scale;
    }
    orow[c] = v;
  }
}

// ---------- 2. weight permute + per-group 4-bit asym quant-dequant ----------
// grid (Nrows, 32): gy<31 -> quantize group of 128 cols; gy==31 -> copy keep cols
__global__ __launch_bounds__(64) void wquant_kernel(const float* __restrict__ W,
                                                    const int* __restrict__ reorder,
                                                    float* __restrict__ out)
{
  int row = blockIdx.x;
  int g = blockIdx.y;
  int t = threadIdx.x;   // 0..63
  const float* wrow = W + (size_t)row * HID;
  float* orow = out + (size_t)row * HID;
  if (g == 31) {
    int c0 = NLOW + t, c1 = NLOW + t + 64;
    orow[c0] = wrow[reorder[c0]];
    orow[c1] = wrow[reorder[c1]];
    return;
  }
  int c0 = g * 128 + t, c1 = c0 + 64;
  float w0 = wrow[reorder[c0]], w1 = wrow[reorder[c1]];
  float mn = fminf(w0, w1), mx = fmaxf(w0, w1);
  mn = wred_min(mn);
  mx = wred_max(mx);
  float scale = fmaxf(mx - mn, 1e-5f) / 15.0f;
  float base = fminf(fmaxf(rintf(-mn / scale), 0.f), 15.f);
  float q0 = fminf(fmaxf(rintf(w0 / scale) + base, 0.f), 15.f) - base;
  float q1 = fminf(fmaxf(rintf(w1 / scale) + base, 0.f), 15.f) - base;
  orow[c0] = q0 * scale;
  orow[c1] = q1 * scale;
}

// ---------- 3. f32 GEMM: C[M,N] = A[M,K] * B[N,K]^T ----------
#define BM 64
#define BN 64
#define BKT 16
__global__ __launch_bounds__(256) void gemm_f32(const float* __restrict__ A,
                                                const float* __restrict__ Bm,
                                                float* __restrict__ C,
                                                int M, int N, int K)
{
  __shared__ float As[BKT][BM + 1];
  __shared__ float Bs[BKT][BN + 1];
  int bx = blockIdx.x, by = blockIdx.y;
  int tid = threadIdx.x;
  int tx = tid & 15, ty = tid >> 4;
  int m0 = by * BM, n0 = bx * BN;
  float acc[4][4] = {};
  for (int k0 = 0; k0 < K; k0 += BKT) {
    #pragma unroll
    for (int i = 0; i < 4; i++) {
      int idx = tid + i * 256;
      int mm = idx >> 4, kk = idx & 15;
      As[kk][mm] = A[(size_t)(m0 + mm) * K + k0 + kk];
      Bs[kk][mm] = Bm[(size_t)(n0 + mm) * K + k0 + kk];
    }
    __syncthreads();
    #pragma unroll
    for (int kk = 0; kk < BKT; kk++) {
      float a[4], b[4];
      #pragma unroll
      for (int i = 0; i < 4; i++) a[i] = As[kk][ty * 4 + i];
      #pragma unroll
      for (int j = 0; j < 4; j++) b[j] = Bs[kk][tx * 4 + j];
      #pragma unroll
      for (int i = 0; i < 4; i++)
        #pragma unroll
        for (int j = 0; j < 4; j++)
          acc[i][j] += a[i] * b[j];
    }
    __syncthreads();
  }
  #pragma unroll
  for (int i = 0; i < 4; i++)
    #pragma unroll
    for (int j = 0; j < 4; j++)
      C[(size_t)(m0 + ty * 4 + i) * N + n0 + tx * 4 + j] = acc[i][j];
}

// ---------- 4. post: RMSNorm / kv 4-bit quant / RoPE, scatter to Q,K,V ----------
// grid (2048, 48) block 128. slot: 0..31 q heads, 32..39 k heads, 40..47 v heads
__global__ __launch_bounds__(128) void post_kernel(const float* __restrict__ qkv,
                                                   const float* __restrict__ cosb,
                                                   const float* __restrict__ sinb,
                                                   const float* __restrict__ qnw,
                                                   const float* __restrict__ knw,
                                                   float* __restrict__ Q,
                                                   float* __restrict__ K,
                                                   float* __restrict__ V)
{
  int m = blockIdx.x;      // b*S + s
  int slot = blockIdx.y;
  int d = threadIdx.x;
  int b = m >> 10, s = m & 1023;
  __shared__ float buf[128];
  __shared__ float red[2];

  size_t csidx = ((size_t)(b * S_LEN + s)) * HD + d;
  float cv = cosb[csidx];
  float sv = sinb[csidx];

  if (slot < NH) {                 // ---- q head ----
    int h = slot;
    float x = qkv[(size_t)m * NQKV + h * HD + d];
    float ss = bsum128(x * x, red, d);
    float xn = x * (1.0f / sqrtf(ss / 128.0f + 1e-6f)) * qnw[d];
    buf[d] = xn;
    __syncthreads();
    float rot = (d < 64) ? -buf[d + 64] : buf[d - 64];
    float o = xn * cv + rot * sv;
    Q[(((size_t)(b * NH + h)) * S_LEN + s) * HD + d] = o;
  } else if (slot < NH + NKV) {    // ---- k head: norm -> quant -> rope ----
    int h = slot - NH;
    float x = qkv[(size_t)m * NQKV + NH * HD + h * HD + d];
    float ss = bsum128(x * x, red, d);
    float xn = x * (1.0f / sqrtf(ss / 128.0f + 1e-6f)) * knw[d];
    float mn = bmin128(xn, red, d);
    float mx = bmax128(xn, red, d);
    float scale = fmaxf(mx - mn, 1e-5f) / 15.0f;
    float base = fminf(fmaxf(rintf(-mn / scale), 0.f), 15.f);
    float xq = (fminf(fmaxf(rintf(xn / scale) + base, 0.f), 15.f) - base) * scale;
    buf[d] = xq;
    __syncthreads();
    float rot = (d < 64) ? -buf[d + 64] : buf[d - 64];
    float o = xq * cv + rot * sv;
    K[(((size_t)(b * NKV + h)) * S_LEN + s) * HD + d] = o;
  } else {                         // ---- v head: quant only ----
    int h = slot - NH - NKV;
    float x = qkv[(size_t)m * NQKV + (NH + NKV) * HD + h * HD + d];
    float mn = bmin128(x, red, d);
    float mx = bmax128(x, red, d);
    float scale = fmaxf(mx - mn, 1e-5f) / 15.0f;
    float base = fminf(fmaxf(rintf(-mn / scale), 0.f), 15.f);
    float xq = (fminf(fmaxf(rintf(x / scale) + base, 0.f), 15.f) - base) * scale;
    V[(((size_t)(b * NKV + h)) * S_LEN + s) * HD + d] = xq;
  }
}

// ---------- 5. causal attention, one block per (b,h,sq), online softmax ----------
__global__ __launch_bounds__(128) void attn_kernel(const float* __restrict__ Q,
                                                   const float* __restrict__ K,
                                                   const float* __restrict__ V,
                                                   float* __restrict__ O)
{
  int idx = blockIdx.x;          // b*NH*S + h*S + sq
  int sq = idx & 1023;
  int h = (idx >> 10) & 31;
  int b = idx >> 15;
  int kvh = h >> 2;
  int t = threadIdx.x;

  __shared__ float qs[HD];
  __shared__ float ps[128];
  __shared__ float red[2];

  const float* qrow = Q + (((size_t)(b * NH + h)) * S_LEN + sq) * HD;
  qs[t] = qrow[t] * 0.08838834764831845f;   // 1/sqrt(128)
  __syncthreads();

  const float* Kb = K + ((size_t)(b * NKV + kvh)) * S_LEN * HD;
  const float* Vb = V + ((size_t)(b * NKV + kvh)) * S_LEN * HD;
  const float4* qs4 = (const float4*)qs;

  float m_run = -INFINITY, l_run = 0.f, acc = 0.f;
  int nk = sq + 1;
  for (int j0 = 0; j0 < nk; j0 += 128) {
    int j = j0 + t;
    float sc = -INFINITY;
    if (j < nk) {
      const float4* kr = (const float4*)(Kb + (size_t)j * HD);
      float a0 = 0.f, a1 = 0.f, a2s = 0.f, a3 = 0.f;
      #pragma unroll
      for (int d4 = 0; d4 < 32; d4++) {
        float4 kvv = kr[d4];
        float4 qv = qs4[d4];
        a0 += qv.x * kvv.x; a1 += qv.y * kvv.y;
        a2s += qv.z * kvv.z; a3 += qv.w * kvv.w;
      }
      sc = (a0 + a1) + (a2s + a3);
    }
    float mt = bmax128(sc, red, t);
    float m_new = fmaxf(m_run, mt);
    float p = (j < nk) ? expf(sc - m_new) : 0.f;
    ps[t] = p;
    float lt = bsum128(p, red, t);   // syncthreads inside makes ps visible
    float alpha = expf(m_run - m_new);   // first tile: exp(-inf)=0
    int jn = min(128, nk - j0);
    float a2 = 0.f;
    const float* vcol = Vb + (size_t)j0 * HD + t;
    for (int jj = 0; jj < jn; jj++) a2 += ps[jj] * vcol[(size_t)jj * HD];
    acc = acc * alpha + a2;
    l_run = l_run * alpha + lt;
    m_run = m_new;
    __syncthreads();   // protect ps before next tile overwrites
  }
  // write in (B,S,NH*HD) layout directly
  O[((size_t)(b * S_LEN + sq)) * (NH * HD) + h * HD + t] = acc / l_run;
}

// ---------- launcher ----------
extern "C" void kernel_launch(void* const* d_in, const int* in_sizes, int n_in,
                              void* d_out, int out_size, void* d_ws, size_t ws_size,
                              hipStream_t stream) {
  const float* hidden = (const float*)d_in[0];
  const float* cosb   = (const float*)d_in[1];
  const float* sinb   = (const float*)d_in[2];
  const float* Wq     = (const float*)d_in[3];
  const float* Wk     = (const float*)d_in[4];
  const float* Wv     = (const float*)d_in[5];
  const float* Wo     = (const float*)d_in[6];
  const float* qnw    = (const float*)d_in[7];
  const float* knw    = (const float*)d_in[8];
  const int*   r_qkv  = (const int*)d_in[9];
  const int*   r_o    = (const int*)d_in[10];
  float* out = (float*)d_out;

  float* ws = (float*)d_ws;
  size_t off = 0;
  float* xq   = ws + off; off += (size_t)M_ROWS * HID;       // 8M
  float* wcat = ws + off; off += (size_t)NQKV * HID;         // 25.2M
  float* qkv  = ws + off; off += (size_t)M_ROWS * NQKV;      // 12.6M
  float* Qb   = ws + off; off += (size_t)2 * NH * S_LEN * HD;   // 8M
  float* Kb   = ws + off; off += (size_t)2 * NKV * S_LEN * HD;  // 2M
  float* Vb   = ws + off; off += (size_t)2 * NKV * S_LEN * HD;  // 2M
  if (ws_size < off * sizeof(float)) return;  // insufficient workspace -> visible failure
  // reuse dead regions
  float* ao  = xq;    // attention output (flat 2048x4096)
  float* oq  = qkv;   // quantized attn output
  float* woq = wcat;  // quantized Wo

  // 1. activation quant (QKV input)
  aquant_kernel<<<M_ROWS, 256, 0, stream>>>(hidden, r_qkv, xq);
  // 2. weight quant into concatenated [6144,4096]
  wquant_kernel<<<dim3(4096, 32), 64, 0, stream>>>(Wq, r_qkv, wcat);
  wquant_kernel<<<dim3(1024, 32), 64, 0, stream>>>(Wk, r_qkv, wcat + (size_t)4096 * HID);
  wquant_kernel<<<dim3(1024, 32), 64, 0, stream>>>(Wv, r_qkv, wcat + (size_t)5120 * HID);
  // 3. fused QKV projection
  gemm_f32<<<dim3(NQKV / BN, M_ROWS / BM), 256, 0, stream>>>(xq, wcat, qkv, M_ROWS, NQKV, HID);
  // 4. norm / kv quant / rope
  post_kernel<<<dim3(M_ROWS, NH + 2 * NKV), 128, 0, stream>>>(qkv, cosb, sinb, qnw, knw, Qb, Kb, Vb);
  // 5. attention
  attn_kernel<<<2 * NH * S_LEN, 128, 0, stream>>>(Qb, Kb, Vb, ao);
  // 6. output quant + Wo quant + O projection
  aquant_kernel<<<M_ROWS, 256, 0, stream>>>(ao, r_o, oq);
  wquant_kernel<<<dim3(4096, 32), 64, 0, stream>>>(Wo, r_o, woq);
  gemm_f32<<<dim3(HID / BN, M_ROWS / BM), 256, 0, stream>>>(oq, woq, out, M_ROWS, HID, HID);
}

// Round 3
// 750.070 us; speedup vs baseline: 8.3343x; 8.3343x over previous
//
#include <hip/hip_runtime.h>
#include <hip/hip_bf16.h>
#include <cstdint>

#define S_LEN 1024
#define HID   4096
#define NH    32
#define NKV   8
#define HD    128
#define NLOW  3968      // HID - SEL
#define M_ROWS 2048     // B*S
#define NQKV  6144      // (NH+2*NKV)*HD

typedef _Float16 f16_t;
typedef _Float16 f16x8 __attribute__((ext_vector_type(8)));
typedef float    f32x4 __attribute__((ext_vector_type(4)));

#define MFMA16(a,b,c) __builtin_amdgcn_mfma_f32_16x16x32_f16(a,b,c,0,0,0)

__device__ inline void gload_lds16(const void* g, void* l) {
  __builtin_amdgcn_global_load_lds(
      (const __attribute__((address_space(1))) void*)g,
      (__attribute__((address_space(3))) void*)l, 16, 0, 0);
}

// ---------- wave reductions (64-wide) ----------
__device__ inline float wred_max(float v){ for(int o=32;o;o>>=1) v=fmaxf(v,__shfl_xor(v,o)); return v; }
__device__ inline float wred_min(float v){ for(int o=32;o;o>>=1) v=fminf(v,__shfl_xor(v,o)); return v; }
__device__ inline float wred_sum(float v){ for(int o=32;o;o>>=1) v+=__shfl_xor(v,o); return v; }

__device__ inline float bsum128(float v, float* red, int t){
  v = wred_sum(v);
  if ((t&63)==0) red[t>>6] = v;
  __syncthreads();
  float r = red[0] + red[1];
  __syncthreads();
  return r;
}
__device__ inline float bmax128(float v, float* red, int t){
  v = wred_max(v);
  if ((t&63)==0) red[t>>6] = v;
  __syncthreads();
  float r = fmaxf(red[0], red[1]);
  __syncthreads();
  return r;
}
__device__ inline float bmin128(float v, float* red, int t){
  v = wred_min(v);
  if ((t&63)==0) red[t>>6] = v;
  __syncthreads();
  float r = fminf(red[0], red[1]);
  __syncthreads();
  return r;
}

// ---------- 1. activation permute + per-row int8 quant ----------
// low cols: store INTEGER q (exact in f16); keep cols: store v/scale.
// GEMM epilogue multiplies output row by scale -> A-side is numerically exact.
__global__ __launch_bounds__(256) void aquant_kernel(const float* __restrict__ X,
                                                     const int* __restrict__ reorder,
                                                     f16_t* __restrict__ out,
                                                     float* __restrict__ sarr)
{
  __shared__ float xs[HID];
  __shared__ float red[256];
  int row = blockIdx.x;
  int t = threadIdx.x;
  const float* xr = X + (size_t)row * HID;
  float amax = 0.f;
  for (int c = t; c < HID; c += 256) {
    float v = xr[reorder[c]];
    xs[c] = v;
    if (c < NLOW) amax = fmaxf(amax, fabsf(v));
  }
  red[t] = amax;
  __syncthreads();
  for (int s = 128; s > 0; s >>= 1) {
    if (t < s) red[t] = fmaxf(red[t], red[t + s]);
    __syncthreads();
  }
  float scale = fmaxf(red[0], 1e-5f) / 127.0f;
  if (t == 0) sarr[row] = scale;
  f16_t* orow = out + (size_t)row * HID;
  for (int c = t; c < HID; c += 256) {
    float v = xs[c];
    if (c < NLOW) {
      float q = fminf(fmaxf(rintf(v / scale), -128.f), 127.f);
      orow[c] = (f16_t)q;            // integer, exact
    } else {
      orow[c] = (f16_t)(v / scale);  // keep col pre-divided by row scale
    }
  }
}

// ---------- 2. weight permute + per-group 4-bit asym quant -> f16 ----------
__global__ __launch_bounds__(64) void wquant_kernel(const float* __restrict__ W,
                                                    const int* __restrict__ reorder,
                                                    f16_t* __restrict__ out)
{
  int row = blockIdx.x;
  int g = blockIdx.y;
  int t = threadIdx.x;   // 0..63
  const float* wrow = W + (size_t)row * HID;
  f16_t* orow = out + (size_t)row * HID;
  if (g == 31) {
    int c0 = NLOW + t, c1 = NLOW + t + 64;
    orow[c0] = (f16_t)wrow[reorder[c0]];
    orow[c1] = (f16_t)wrow[reorder[c1]];
    return;
  }
  int c0 = g * 128 + t, c1 = c0 + 64;
  float w0 = wrow[reorder[c0]], w1 = wrow[reorder[c1]];
  float mn = wred_min(fminf(w0, w1));
  float mx = wred_max(fmaxf(w0, w1));
  float scale = fmaxf(mx - mn, 1e-5f) / 15.0f;
  float base = fminf(fmaxf(rintf(-mn / scale), 0.f), 15.f);
  float q0 = fminf(fmaxf(rintf(w0 / scale) + base, 0.f), 15.f) - base;
  float q1 = fminf(fmaxf(rintf(w1 / scale) + base, 0.f), 15.f) - base;
  orow[c0] = (f16_t)(q0 * scale);
  orow[c1] = (f16_t)(q1 * scale);
}

// ---------- 3. f16 MFMA GEMM: C[M,N] f32 = rowscale[m] * (A[M,K] * B[N,K]^T) ----------
__global__ __launch_bounds__(256) void gemm_bt_f16(const f16_t* __restrict__ A,
                                                   const f16_t* __restrict__ B,
                                                   float* __restrict__ C,
                                                   const float* __restrict__ rowscale,
                                                   int M, int N, int K)
{
  __shared__ f16_t As[128 * 32];
  __shared__ f16_t Bs[128 * 32];
  int tid = threadIdx.x;
  int w = tid >> 6, lane = tid & 63;
  int g = lane >> 4, l15 = lane & 15;
  int m0 = blockIdx.y * 128, n0 = blockIdx.x * 128;
  int wm = (w >> 1) * 64, wn = (w & 1) * 64;

  f32x4 zf = {0.f, 0.f, 0.f, 0.f};
  f32x4 acc[4][4];
  #pragma unroll
  for (int m = 0; m < 4; m++)
    #pragma unroll
    for (int n = 0; n < 4; n++) acc[m][n] = zf;

  int srow = lane >> 2, scol = lane & 3;      // staging: 16 rows x 4 slots per 1KB chunk

  for (int k0 = 0; k0 < K; k0 += 32) {
    #pragma unroll
    for (int i = 0; i < 2; i++) {
      int ca = w + 4 * i;
      int rowA = ca * 16 + srow;
      gload_lds16(A + (size_t)(m0 + rowA) * K + k0 + scol * 8, As + ca * 512);
      gload_lds16(B + (size_t)(n0 + rowA) * K + k0 + scol * 8, Bs + ca * 512);
    }
    __syncthreads();
    f16x8 af[4], bf[4];
    #pragma unroll
    for (int m = 0; m < 4; m++)
      af[m] = *(const f16x8*)(As + (wm + m * 16 + l15) * 32 + g * 8);
    #pragma unroll
    for (int n = 0; n < 4; n++)
      bf[n] = *(const f16x8*)(Bs + (wn + n * 16 + l15) * 32 + g * 8);
    #pragma unroll
    for (int m = 0; m < 4; m++)
      #pragma unroll
      for (int n = 0; n < 4; n++)
        acc[m][n] = MFMA16(af[m], bf[n], acc[m][n]);
    __syncthreads();
  }
  int rb = g * 4;
  #pragma unroll
  for (int m = 0; m < 4; m++)
    #pragma unroll
    for (int j = 0; j < 4; j++) {
      int row = m0 + wm + m * 16 + rb + j;
      float sav = rowscale[row];
      #pragma unroll
      for (int n = 0; n < 4; n++)
        C[(size_t)row * N + n0 + wn + n * 16 + l15] = acc[m][n][j] * sav;
    }
}

// ---------- 4. post: RMSNorm / kv 4-bit quant / RoPE -> f16 Q,K,V^T ----------
__global__ __launch_bounds__(128) void post_kernel(const float* __restrict__ qkv,
                                                   const float* __restrict__ cosb,
                                                   const float* __restrict__ sinb,
                                                   const float* __restrict__ qnw,
                                                   const float* __restrict__ knw,
                                                   f16_t* __restrict__ Q,
                                                   f16_t* __restrict__ K,
                                                   f16_t* __restrict__ Vt)
{
  int m = blockIdx.x;      // b*S + s
  int slot = blockIdx.y;
  int d = threadIdx.x;
  int b = m >> 10, s = m & 1023;
  __shared__ float buf[128];
  __shared__ float red[2];

  float cv = cosb[(size_t)m * HD + d];
  float sv = sinb[(size_t)m * HD + d];

  if (slot < NH) {                 // q: norm -> rope -> *1/sqrt(HD)
    int h = slot;
    float x = qkv[(size_t)m * NQKV + h * HD + d];
    float ss = bsum128(x * x, red, d);
    float xn = x * (1.0f / sqrtf(ss / 128.0f + 1e-6f)) * qnw[d];
    buf[d] = xn;
    __syncthreads();
    float rot = (d < 64) ? -buf[d + 64] : buf[d - 64];
    float o = (xn * cv + rot * sv) * 0.08838834764831845f;
    Q[(((size_t)(b * NH + h)) * S_LEN + s) * HD + d] = (f16_t)o;
  } else if (slot < NH + NKV) {    // k: norm -> quant -> rope
    int h = slot - NH;
    float x = qkv[(size_t)m * NQKV + NH * HD + h * HD + d];
    float ss = bsum128(x * x, red, d);
    float xn = x * (1.0f / sqrtf(ss / 128.0f + 1e-6f)) * knw[d];
    float mn = bmin128(xn, red, d);
    float mx = bmax128(xn, red, d);
    float scale = fmaxf(mx - mn, 1e-5f) / 15.0f;
    float base = fminf(fmaxf(rintf(-mn / scale), 0.f), 15.f);
    float xq = (fminf(fmaxf(rintf(xn / scale) + base, 0.f), 15.f) - base) * scale;
    buf[d] = xq;
    __syncthreads();
    float rot = (d < 64) ? -buf[d + 64] : buf[d - 64];
    float o = xq * cv + rot * sv;
    K[(((size_t)(b * NKV + h)) * S_LEN + s) * HD + d] = (f16_t)o;
  } else {                         // v: quant only, store transposed [HD][S]
    int h = slot - NH - NKV;
    float x = qkv[(size_t)m * NQKV + (NH + NKV) * HD + h * HD + d];
    float mn = bmin128(x, red, d);
    float mx = bmax128(x, red, d);
    float scale = fmaxf(mx - mn, 1e-5f) / 15.0f;
    float base = fminf(fmaxf(rintf(-mn / scale), 0.f), 15.f);
    float xq = (fminf(fmaxf(rintf(x / scale) + base, 0.f), 15.f) - base) * scale;
    Vt[((size_t)(b * NKV + h) * HD + d) * S_LEN + s] = (f16_t)xq;
  }
}

// ---------- 5. flash attention, f16 MFMA ----------
// block: 256 thr (4 waves), 64 q-rows (16/wave), KBLK=64.
// K LDS [64][128] swz, V^T LDS [128][64] swz, P per-wave [16][64] swz.
__global__ __launch_bounds__(256) void attn_mfma(const f16_t* __restrict__ Q,
                                                 const f16_t* __restrict__ Kg,
                                                 const f16_t* __restrict__ Vg,
                                                 float* __restrict__ O)
{
  __shared__ f16_t Ks[64 * 128];
  __shared__ f16_t Vs[128 * 64];
  __shared__ f16_t Ps[4 * 16 * 64];
  int tid = threadIdx.x;
  int w = tid >> 6, lane = tid & 63;
  int g = lane >> 4, l15 = lane & 15;
  int flat = blockIdx.x;              // qb in high bits -> mixed tile counts per CU
  int h = flat & 31, b = (flat >> 5) & 1, qb = flat >> 6;
  int kvh = h >> 2;
  int q0 = qb * 64;

  const f16_t* Qp = Q + (size_t)(b * NH + h) * S_LEN * HD;
  const f16_t* Kp = Kg + (size_t)(b * NKV + kvh) * S_LEN * HD;
  const f16_t* Vp = Vg + (size_t)(b * NKV + kvh) * HD * S_LEN;

  int qrow = q0 + w * 16 + l15;
  f16x8 qf[4];
  #pragma unroll
  for (int c = 0; c < 4; c++)
    qf[c] = *(const f16x8*)(Qp + (size_t)qrow * HD + c * 32 + g * 8);

  f32x4 zf = {0.f, 0.f, 0.f, 0.f};
  f32x4 oacc[8];
  #pragma unroll
  for (int nd = 0; nd < 8; nd++) oacc[nd] = zf;
  float mrun[4], lrun[4];
  #pragma unroll
  for (int j = 0; j < 4; j++) { mrun[j] = -INFINITY; lrun[j] = 0.f; }

  f16_t* pw = Ps + w * 1024;
  int ntiles = qb + 1;
  for (int it = 0; it < ntiles; it++) {
    int kt = it * 64;
    // stage K tile: 16 chunks of 1KB (4 rows x 16 slots), src slot pre-swizzled
    #pragma unroll
    for (int i = 0; i < 4; i++) {
      int c = w + 4 * i;
      int row = c * 4 + g;
      int ss = l15 ^ (row & 7);
      gload_lds16(Kp + (size_t)(kt + row) * HD + ss * 8, Ks + c * 512);
    }
    // stage V^T tile: 16 chunks (8 rows x 8 slots)
    #pragma unroll
    for (int i = 0; i < 4; i++) {
      int c = w + 4 * i;
      int row = c * 8 + (lane >> 3);
      int ss = (lane & 7) ^ (row & 7);
      gload_lds16(Vp + (size_t)row * S_LEN + kt + ss * 8, Vs + c * 512);
    }
    __syncthreads();

    // QK^T: S[16q][64k], rows(reg)=q, cols(lane&15)=k
    f32x4 sv[4];
    #pragma unroll
    for (int nk = 0; nk < 4; nk++) sv[nk] = zf;
    #pragma unroll
    for (int nk = 0; nk < 4; nk++) {
      int krow = nk * 16 + l15;
      #pragma unroll
      for (int c = 0; c < 4; c++) {
        f16x8 kf = *(const f16x8*)(Ks + krow * 128 + ((c * 4 + g) ^ (krow & 7)) * 8);
        sv[nk] = MFMA16(qf[c], kf, sv[nk]);
      }
    }
    // causal mask
    #pragma unroll
    for (int nk = 0; nk < 4; nk++) {
      int kcol = kt + nk * 16 + l15;
      #pragma unroll
      for (int j = 0; j < 4; j++) {
        int qr = q0 + w * 16 + g * 4 + j;
        if (kcol > qr) sv[nk][j] = -1e30f;
      }
    }
    // online softmax (row stats live in the 16 lanes of each lane-group)
    float alpha[4];
    #pragma unroll
    for (int j = 0; j < 4; j++) {
      float mr = fmaxf(fmaxf(sv[0][j], sv[1][j]), fmaxf(sv[2][j], sv[3][j]));
      mr = fmaxf(mr, __shfl_xor(mr, 1));
      mr = fmaxf(mr, __shfl_xor(mr, 2));
      mr = fmaxf(mr, __shfl_xor(mr, 4));
      mr = fmaxf(mr, __shfl_xor(mr, 8));
      float mnew = fmaxf(mrun[j], mr);
      alpha[j] = __expf(mrun[j] - mnew);
      float lt = 0.f;
      #pragma unroll
      for (int nk = 0; nk < 4; nk++) {
        float p = __expf(sv[nk][j] - mnew);
        sv[nk][j] = p;
        lt += p;
      }
      lt += __shfl_xor(lt, 1);
      lt += __shfl_xor(lt, 2);
      lt += __shfl_xor(lt, 4);
      lt += __shfl_xor(lt, 8);
      lrun[j] = lrun[j] * alpha[j] + lt;
      mrun[j] = mnew;
    }
    // write P (f16, swizzled rows of 64 elems)
    #pragma unroll
    for (int j = 0; j < 4; j++) {
      int ql = g * 4 + j;
      #pragma unroll
      for (int nk = 0; nk < 4; nk++) {
        int kl = nk * 16 + l15;
        int ss = (kl >> 3) ^ (ql & 7);
        pw[ql * 64 + ss * 8 + (kl & 7)] = (f16_t)sv[nk][j];
      }
    }
    // rescale O
    #pragma unroll
    for (int nd = 0; nd < 8; nd++)
      #pragma unroll
      for (int j = 0; j < 4; j++) oacc[nd][j] *= alpha[j];
    // PV: O[16q][128d] += P[16q][64k] * V[64k][128d]
    #pragma unroll
    for (int kc = 0; kc < 2; kc++) {
      f16x8 pf = *(const f16x8*)(pw + l15 * 64 + ((kc * 4 + g) ^ (l15 & 7)) * 8);
      #pragma unroll
      for (int nd = 0; nd < 8; nd++) {
        int d = nd * 16 + l15;
        f16x8 vf = *(const f16x8*)(Vs + d * 64 + ((kc * 4 + g) ^ (d & 7)) * 8);
        oacc[nd] = MFMA16(pf, vf, oacc[nd]);
      }
    }
    __syncthreads();
  }
  // epilogue: write (B,S,NH*HD) f32
  #pragma unroll
  for (int j = 0; j < 4; j++) {
    float invl = 1.0f / lrun[j];
    float* orow = O + ((size_t)(b * S_LEN) + q0 + w * 16 + g * 4 + j) * (NH * HD) + h * HD + l15;
    #pragma unroll
    for (int nd = 0; nd < 8; nd++) orow[nd * 16] = oacc[nd][j] * invl;
  }
}

// ---------- launcher ----------
extern "C" void kernel_launch(void* const* d_in, const int* in_sizes, int n_in,
                              void* d_out, int out_size, void* d_ws, size_t ws_size,
                              hipStream_t stream) {
  const float* hidden = (const float*)d_in[0];
  const float* cosb   = (const float*)d_in[1];
  const float* sinb   = (const float*)d_in[2];
  const float* Wq     = (const float*)d_in[3];
  const float* Wk     = (const float*)d_in[4];
  const float* Wv     = (const float*)d_in[5];
  const float* Wo     = (const float*)d_in[6];
  const float* qnw    = (const float*)d_in[7];
  const float* knw    = (const float*)d_in[8];
  const int*   r_qkv  = (const int*)d_in[9];
  const int*   r_o    = (const int*)d_in[10];
  float* out = (float*)d_out;

  f16_t* xq   = (f16_t*)d_ws;                                    // [2048][4096] f16
  f16_t* wcat = xq + (size_t)M_ROWS * HID;                       // [6144][4096] f16
  float* qkv  = (float*)(wcat + (size_t)NQKV * HID);             // [2048][6144] f32
  f16_t* Qb   = (f16_t*)(qkv + (size_t)M_ROWS * NQKV);           // [2*32*1024][128] f16
  f16_t* Kb   = Qb + (size_t)2 * NH * S_LEN * HD;                // [2*8*1024][128] f16
  f16_t* Vt   = Kb + (size_t)2 * NKV * S_LEN * HD;               // [2*8][128][1024] f16
  float* sa1  = (float*)(Vt + (size_t)2 * NKV * S_LEN * HD);     // [2048] f32
  float* sa2  = sa1 + M_ROWS;                                    // [2048] f32
  size_t needed = (size_t)((char*)(sa2 + M_ROWS) - (char*)d_ws);
  if (ws_size < needed) return;
  float* ao  = qkv;    // alias: attention output [2048][4096] f32 (qkv dead)
  f16_t* oq  = xq;     // alias: quantized attn output
  f16_t* woq = wcat;   // alias: quantized Wo

  aquant_kernel<<<M_ROWS, 256, 0, stream>>>(hidden, r_qkv, xq, sa1);
  wquant_kernel<<<dim3(4096, 32), 64, 0, stream>>>(Wq, r_qkv, wcat);
  wquant_kernel<<<dim3(1024, 32), 64, 0, stream>>>(Wk, r_qkv, wcat + (size_t)4096 * HID);
  wquant_kernel<<<dim3(1024, 32), 64, 0, stream>>>(Wv, r_qkv, wcat + (size_t)5120 * HID);
  gemm_bt_f16<<<dim3(NQKV / 128, M_ROWS / 128), 256, 0, stream>>>(xq, wcat, qkv, sa1, M_ROWS, NQKV, HID);
  post_kernel<<<dim3(M_ROWS, NH + 2 * NKV), 128, 0, stream>>>(qkv, cosb, sinb, qnw, knw, Qb, Kb, Vt);
  attn_mfma<<<1024, 256, 0, stream>>>(Qb, Kb, Vt, ao);
  aquant_kernel<<<M_ROWS, 256, 0, stream>>>(ao, r_o, oq, sa2);
  wquant_kernel<<<dim3(4096, 32), 64, 0, stream>>>(Wo, r_o, woq);
  gemm_bt_f16<<<dim3(HID / 128, M_ROWS / 128), 256, 0, stream>>>(oq, woq, out, sa2, M_ROWS, HID, HID);
}

// Round 4
// 473.368 us; speedup vs baseline: 13.2061x; 1.5845x over previous
//
#include <hip/hip_runtime.h>
#include <hip/hip_bf16.h>
#include <cstdint>

#define S_LEN 1024
#define HID   4096
#define NH    32
#define NKV   8
#define HD    128
#define NLOW  3968      // HID - SEL
#define M_ROWS 2048     // B*S
#define NQKV  6144      // (NH+2*NKV)*HD

typedef _Float16 f16_t;
typedef _Float16 f16x8 __attribute__((ext_vector_type(8)));
typedef float    f32x4 __attribute__((ext_vector_type(4)));

#define MFMA16(a,b,c) __builtin_amdgcn_mfma_f32_16x16x32_f16(a,b,c,0,0,0)

__device__ inline void gload_lds16(const void* g, void* l) {
  __builtin_amdgcn_global_load_lds(
      (const __attribute__((address_space(1))) void*)g,
      (__attribute__((address_space(3))) void*)l, 16, 0, 0);
}

// ---------- wave reductions (64-wide) ----------
__device__ inline float wred_max(float v){ for(int o=32;o;o>>=1) v=fmaxf(v,__shfl_xor(v,o)); return v; }
__device__ inline float wred_min(float v){ for(int o=32;o;o>>=1) v=fminf(v,__shfl_xor(v,o)); return v; }
__device__ inline float wred_sum(float v){ for(int o=32;o;o>>=1) v+=__shfl_xor(v,o); return v; }

__device__ inline float bsum128(float v, float* red, int t){
  v = wred_sum(v);
  if ((t&63)==0) red[t>>6] = v;
  __syncthreads();
  float r = red[0] + red[1];
  __syncthreads();
  return r;
}
__device__ inline float bmax128(float v, float* red, int t){
  v = wred_max(v);
  if ((t&63)==0) red[t>>6] = v;
  __syncthreads();
  float r = fmaxf(red[0], red[1]);
  __syncthreads();
  return r;
}
__device__ inline float bmin128(float v, float* red, int t){
  v = wred_min(v);
  if ((t&63)==0) red[t>>6] = v;
  __syncthreads();
  float r = fminf(red[0], red[1]);
  __syncthreads();
  return r;
}

// ---------- 1. activation permute + per-row int8 quant ----------
// low cols: store INTEGER q (exact in f16); keep cols: store v/scale.
// GEMM epilogue multiplies output row by scale -> A-side is numerically exact.
__global__ __launch_bounds__(256) void aquant_kernel(const float* __restrict__ X,
                                                     const int* __restrict__ reorder,
                                                     f16_t* __restrict__ out,
                                                     float* __restrict__ sarr)
{
  __shared__ float xs[HID];
  __shared__ float red[256];
  int row = blockIdx.x;
  int t = threadIdx.x;
  const float* xr = X + (size_t)row * HID;
  float amax = 0.f;
  for (int c = t; c < HID; c += 256) {
    float v = xr[reorder[c]];
    xs[c] = v;
    if (c < NLOW) amax = fmaxf(amax, fabsf(v));
  }
  red[t] = amax;
  __syncthreads();
  for (int s = 128; s > 0; s >>= 1) {
    if (t < s) red[t] = fmaxf(red[t], red[t + s]);
    __syncthreads();
  }
  float scale = fmaxf(red[0], 1e-5f) / 127.0f;
  if (t == 0) sarr[row] = scale;
  f16_t* orow = out + (size_t)row * HID;
  for (int c = t; c < HID; c += 256) {
    float v = xs[c];
    if (c < NLOW) {
      float q = fminf(fmaxf(rintf(v / scale), -128.f), 127.f);
      orow[c] = (f16_t)q;            // integer, exact
    } else {
      orow[c] = (f16_t)(v / scale);  // keep col pre-divided by row scale
    }
  }
}

// ---------- 2. weight permute + per-group 4-bit asym quant -> f16 ----------
// One block per row: stage row in LDS (coalesced), gather from LDS.
// Thread t owns permuted cols [16t, 16t+16); 8 lanes = one 128-col group.
__global__ __launch_bounds__(256) void wquant_kernel(const float* __restrict__ W,
                                                     const int* __restrict__ reorder,
                                                     f16_t* __restrict__ out)
{
  __shared__ float xs[HID];
  int row = blockIdx.x;
  int t = threadIdx.x;
  const f32x4* wrow4 = (const f32x4*)(W + (size_t)row * HID);
  f32x4* xs4 = (f32x4*)xs;
  #pragma unroll
  for (int i = 0; i < 4; i++)
    xs4[t + i * 256] = wrow4[t + i * 256];
  __syncthreads();

  int c0 = t * 16;
  float v[16];
  #pragma unroll
  for (int j = 0; j < 16; j++)
    v[j] = xs[reorder[c0 + j]];

  f16_t* orow = out + (size_t)row * HID;
  f16x8 o0, o1;
  if (c0 < NLOW) {
    float mn = v[0], mx = v[0];
    #pragma unroll
    for (int j = 1; j < 16; j++) { mn = fminf(mn, v[j]); mx = fmaxf(mx, v[j]); }
    #pragma unroll
    for (int o = 1; o <= 4; o <<= 1) {
      mn = fminf(mn, __shfl_xor(mn, o));
      mx = fmaxf(mx, __shfl_xor(mx, o));
    }
    float scale = fmaxf(mx - mn, 1e-5f) / 15.0f;
    float base = fminf(fmaxf(rintf(-mn / scale), 0.f), 15.f);
    #pragma unroll
    for (int j = 0; j < 8; j++) {
      o0[j] = (f16_t)((fminf(fmaxf(rintf(v[j] / scale) + base, 0.f), 15.f) - base) * scale);
      o1[j] = (f16_t)((fminf(fmaxf(rintf(v[j + 8] / scale) + base, 0.f), 15.f) - base) * scale);
    }
  } else {
    #pragma unroll
    for (int j = 0; j < 8; j++) { o0[j] = (f16_t)v[j]; o1[j] = (f16_t)v[j + 8]; }
  }
  *(f16x8*)(orow + c0) = o0;
  *(f16x8*)(orow + c0 + 8) = o1;
}

// ---------- 3. f16 MFMA GEMM: C[M,N] f32 = rowscale[m] * (A[M,K] * B[N,K]^T) ----------
__global__ __launch_bounds__(256) void gemm_bt_f16(const f16_t* __restrict__ A,
                                                   const f16_t* __restrict__ B,
                                                   float* __restrict__ C,
                                                   const float* __restrict__ rowscale,
                                                   int M, int N, int K)
{
  __shared__ f16_t As[128 * 32];
  __shared__ f16_t Bs[128 * 32];
  int tid = threadIdx.x;
  int w = tid >> 6, lane = tid & 63;
  int g = lane >> 4, l15 = lane & 15;
  int m0 = blockIdx.y * 128, n0 = blockIdx.x * 128;
  int wm = (w >> 1) * 64, wn = (w & 1) * 64;

  f32x4 zf = {0.f, 0.f, 0.f, 0.f};
  f32x4 acc[4][4];
  #pragma unroll
  for (int m = 0; m < 4; m++)
    #pragma unroll
    for (int n = 0; n < 4; n++) acc[m][n] = zf;

  int srow = lane >> 2, scol = lane & 3;      // staging: 16 rows x 4 slots per 1KB chunk

  for (int k0 = 0; k0 < K; k0 += 32) {
    #pragma unroll
    for (int i = 0; i < 2; i++) {
      int ca = w + 4 * i;
      int rowA = ca * 16 + srow;
      gload_lds16(A + (size_t)(m0 + rowA) * K + k0 + scol * 8, As + ca * 512);
      gload_lds16(B + (size_t)(n0 + rowA) * K + k0 + scol * 8, Bs + ca * 512);
    }
    __syncthreads();
    f16x8 af[4], bf[4];
    #pragma unroll
    for (int m = 0; m < 4; m++)
      af[m] = *(const f16x8*)(As + (wm + m * 16 + l15) * 32 + g * 8);
    #pragma unroll
    for (int n = 0; n < 4; n++)
      bf[n] = *(const f16x8*)(Bs + (wn + n * 16 + l15) * 32 + g * 8);
    #pragma unroll
    for (int m = 0; m < 4; m++)
      #pragma unroll
      for (int n = 0; n < 4; n++)
        acc[m][n] = MFMA16(af[m], bf[n], acc[m][n]);
    __syncthreads();
  }
  int rb = g * 4;
  #pragma unroll
  for (int m = 0; m < 4; m++)
    #pragma unroll
    for (int j = 0; j < 4; j++) {
      int row = m0 + wm + m * 16 + rb + j;
      float sav = rowscale[row];
      #pragma unroll
      for (int n = 0; n < 4; n++)
        C[(size_t)row * N + n0 + wn + n * 16 + l15] = acc[m][n][j] * sav;
    }
}

// ---------- 4. post: RMSNorm / kv 4-bit quant / RoPE -> f16 Q,K,V^T ----------
__global__ __launch_bounds__(128) void post_kernel(const float* __restrict__ qkv,
                                                   const float* __restrict__ cosb,
                                                   const float* __restrict__ sinb,
                                                   const float* __restrict__ qnw,
                                                   const float* __restrict__ knw,
                                                   f16_t* __restrict__ Q,
                                                   f16_t* __restrict__ K,
                                                   f16_t* __restrict__ Vt)
{
  int m = blockIdx.x;      // b*S + s
  int slot = blockIdx.y;
  int d = threadIdx.x;
  int b = m >> 10, s = m & 1023;
  __shared__ float buf[128];
  __shared__ float red[2];

  float cv = cosb[(size_t)m * HD + d];
  float sv = sinb[(size_t)m * HD + d];

  if (slot < NH) {                 // q: norm -> rope -> *1/sqrt(HD)
    int h = slot;
    float x = qkv[(size_t)m * NQKV + h * HD + d];
    float ss = bsum128(x * x, red, d);
    float xn = x * (1.0f / sqrtf(ss / 128.0f + 1e-6f)) * qnw[d];
    buf[d] = xn;
    __syncthreads();
    float rot = (d < 64) ? -buf[d + 64] : buf[d - 64];
    float o = (xn * cv + rot * sv) * 0.08838834764831845f;
    Q[(((size_t)(b * NH + h)) * S_LEN + s) * HD + d] = (f16_t)o;
  } else if (slot < NH + NKV) {    // k: norm -> quant -> rope
    int h = slot - NH;
    float x = qkv[(size_t)m * NQKV + NH * HD + h * HD + d];
    float ss = bsum128(x * x, red, d);
    float xn = x * (1.0f / sqrtf(ss / 128.0f + 1e-6f)) * knw[d];
    float mn = bmin128(xn, red, d);
    float mx = bmax128(xn, red, d);
    float scale = fmaxf(mx - mn, 1e-5f) / 15.0f;
    float base = fminf(fmaxf(rintf(-mn / scale), 0.f), 15.f);
    float xq = (fminf(fmaxf(rintf(xn / scale) + base, 0.f), 15.f) - base) * scale;
    buf[d] = xq;
    __syncthreads();
    float rot = (d < 64) ? -buf[d + 64] : buf[d - 64];
    float o = xq * cv + rot * sv;
    K[(((size_t)(b * NKV + h)) * S_LEN + s) * HD + d] = (f16_t)o;
  } else {                         // v: quant only, store transposed [HD][S]
    int h = slot - NH - NKV;
    float x = qkv[(size_t)m * NQKV + (NH + NKV) * HD + h * HD + d];
    float mn = bmin128(x, red, d);
    float mx = bmax128(x, red, d);
    float scale = fmaxf(mx - mn, 1e-5f) / 15.0f;
    float base = fminf(fmaxf(rintf(-mn / scale), 0.f), 15.f);
    float xq = (fminf(fmaxf(rintf(x / scale) + base, 0.f), 15.f) - base) * scale;
    Vt[((size_t)(b * NKV + h) * HD + d) * S_LEN + s] = (f16_t)xq;
  }
}

// ---------- 5. flash attention, f16 MFMA ----------
// block: 256 thr (4 waves), 64 q-rows (16/wave), KBLK=64.
// K LDS [64][128] swz, V^T LDS [128][64] swz, P per-wave [16][64] swz.
__global__ __launch_bounds__(256) void attn_mfma(const f16_t* __restrict__ Q,
                                                 const f16_t* __restrict__ Kg,
                                                 const f16_t* __restrict__ Vg,
                                                 float* __restrict__ O)
{
  __shared__ f16_t Ks[64 * 128];
  __shared__ f16_t Vs[128 * 64];
  __shared__ f16_t Ps[4 * 16 * 64];
  int tid = threadIdx.x;
  int w = tid >> 6, lane = tid & 63;
  int g = lane >> 4, l15 = lane & 15;
  int flat = blockIdx.x;              // qb in high bits -> mixed tile counts per CU
  int h = flat & 31, b = (flat >> 5) & 1, qb = flat >> 6;
  int kvh = h >> 2;
  int q0 = qb * 64;

  const f16_t* Qp = Q + (size_t)(b * NH + h) * S_LEN * HD;
  const f16_t* Kp = Kg + (size_t)(b * NKV + kvh) * S_LEN * HD;
  const f16_t* Vp = Vg + (size_t)(b * NKV + kvh) * HD * S_LEN;

  int qrow = q0 + w * 16 + l15;
  f16x8 qf[4];
  #pragma unroll
  for (int c = 0; c < 4; c++)
    qf[c] = *(const f16x8*)(Qp + (size_t)qrow * HD + c * 32 + g * 8);

  f32x4 zf = {0.f, 0.f, 0.f, 0.f};
  f32x4 oacc[8];
  #pragma unroll
  for (int nd = 0; nd < 8; nd++) oacc[nd] = zf;
  float mrun[4], lrun[4];
  #pragma unroll
  for (int j = 0; j < 4; j++) { mrun[j] = -INFINITY; lrun[j] = 0.f; }

  f16_t* pw = Ps + w * 1024;
  int ntiles = qb + 1;
  for (int it = 0; it < ntiles; it++) {
    int kt = it * 64;
    // stage K tile: 16 chunks of 1KB (4 rows x 16 slots), src slot pre-swizzled
    #pragma unroll
    for (int i = 0; i < 4; i++) {
      int c = w + 4 * i;
      int row = c * 4 + g;
      int ss = l15 ^ (row & 7);
      gload_lds16(Kp + (size_t)(kt + row) * HD + ss * 8, Ks + c * 512);
    }
    // stage V^T tile: 16 chunks (8 rows x 8 slots)
    #pragma unroll
    for (int i = 0; i < 4; i++) {
      int c = w + 4 * i;
      int row = c * 8 + (lane >> 3);
      int ss = (lane & 7) ^ (row & 7);
      gload_lds16(Vp + (size_t)row * S_LEN + kt + ss * 8, Vs + c * 512);
    }
    __syncthreads();

    // QK^T: S[16q][64k], rows(reg)=q, cols(lane&15)=k
    f32x4 sv[4];
    #pragma unroll
    for (int nk = 0; nk < 4; nk++) sv[nk] = zf;
    #pragma unroll
    for (int nk = 0; nk < 4; nk++) {
      int krow = nk * 16 + l15;
      #pragma unroll
      for (int c = 0; c < 4; c++) {
        f16x8 kf = *(const f16x8*)(Ks + krow * 128 + ((c * 4 + g) ^ (krow & 7)) * 8);
        sv[nk] = MFMA16(qf[c], kf, sv[nk]);
      }
    }
    // causal mask
    #pragma unroll
    for (int nk = 0; nk < 4; nk++) {
      int kcol = kt + nk * 16 + l15;
      #pragma unroll
      for (int j = 0; j < 4; j++) {
        int qr = q0 + w * 16 + g * 4 + j;
        if (kcol > qr) sv[nk][j] = -1e30f;
      }
    }
    // online softmax (row stats live in the 16 lanes of each lane-group)
    float alpha[4];
    #pragma unroll
    for (int j = 0; j < 4; j++) {
      float mr = fmaxf(fmaxf(sv[0][j], sv[1][j]), fmaxf(sv[2][j], sv[3][j]));
      mr = fmaxf(mr, __shfl_xor(mr, 1));
      mr = fmaxf(mr, __shfl_xor(mr, 2));
      mr = fmaxf(mr, __shfl_xor(mr, 4));
      mr = fmaxf(mr, __shfl_xor(mr, 8));
      float mnew = fmaxf(mrun[j], mr);
      alpha[j] = __expf(mrun[j] - mnew);
      float lt = 0.f;
      #pragma unroll
      for (int nk = 0; nk < 4; nk++) {
        float p = __expf(sv[nk][j] - mnew);
        sv[nk][j] = p;
        lt += p;
      }
      lt += __shfl_xor(lt, 1);
      lt += __shfl_xor(lt, 2);
      lt += __shfl_xor(lt, 4);
      lt += __shfl_xor(lt, 8);
      lrun[j] = lrun[j] * alpha[j] + lt;
      mrun[j] = mnew;
    }
    // write P (f16, swizzled rows of 64 elems)
    #pragma unroll
    for (int j = 0; j < 4; j++) {
      int ql = g * 4 + j;
      #pragma unroll
      for (int nk = 0; nk < 4; nk++) {
        int kl = nk * 16 + l15;
        int ss = (kl >> 3) ^ (ql & 7);
        pw[ql * 64 + ss * 8 + (kl & 7)] = (f16_t)sv[nk][j];
      }
    }
    // rescale O
    #pragma unroll
    for (int nd = 0; nd < 8; nd++)
      #pragma unroll
      for (int j = 0; j < 4; j++) oacc[nd][j] *= alpha[j];
    // PV: O[16q][128d] += P[16q][64k] * V[64k][128d]
    #pragma unroll
    for (int kc = 0; kc < 2; kc++) {
      f16x8 pf = *(const f16x8*)(pw + l15 * 64 + ((kc * 4 + g) ^ (l15 & 7)) * 8);
      #pragma unroll
      for (int nd = 0; nd < 8; nd++) {
        int d = nd * 16 + l15;
        f16x8 vf = *(const f16x8*)(Vs + d * 64 + ((kc * 4 + g) ^ (d & 7)) * 8);
        oacc[nd] = MFMA16(pf, vf, oacc[nd]);
      }
    }
    __syncthreads();
  }
  // epilogue: write (B,S,NH*HD) f32
  #pragma unroll
  for (int j = 0; j < 4; j++) {
    float invl = 1.0f / lrun[j];
    float* orow = O + ((size_t)(b * S_LEN) + q0 + w * 16 + g * 4 + j) * (NH * HD) + h * HD + l15;
    #pragma unroll
    for (int nd = 0; nd < 8; nd++) orow[nd * 16] = oacc[nd][j] * invl;
  }
}

// ---------- launcher ----------
extern "C" void kernel_launch(void* const* d_in, const int* in_sizes, int n_in,
                              void* d_out, int out_size, void* d_ws, size_t ws_size,
                              hipStream_t stream) {
  const float* hidden = (const float*)d_in[0];
  const float* cosb   = (const float*)d_in[1];
  const float* sinb   = (const float*)d_in[2];
  const float* Wq     = (const float*)d_in[3];
  const float* Wk     = (const float*)d_in[4];
  const float* Wv     = (const float*)d_in[5];
  const float* Wo     = (const float*)d_in[6];
  const float* qnw    = (const float*)d_in[7];
  const float* knw    = (const float*)d_in[8];
  const int*   r_qkv  = (const int*)d_in[9];
  const int*   r_o    = (const int*)d_in[10];
  float* out = (float*)d_out;

  f16_t* xq   = (f16_t*)d_ws;                                    // [2048][4096] f16
  f16_t* wcat = xq + (size_t)M_ROWS * HID;                       // [6144][4096] f16
  float* qkv  = (float*)(wcat + (size_t)NQKV * HID);             // [2048][6144] f32
  f16_t* Qb   = (f16_t*)(qkv + (size_t)M_ROWS * NQKV);           // [2*32*1024][128] f16
  f16_t* Kb   = Qb + (size_t)2 * NH * S_LEN * HD;                // [2*8*1024][128] f16
  f16_t* Vt   = Kb + (size_t)2 * NKV * S_LEN * HD;               // [2*8][128][1024] f16
  float* sa1  = (float*)(Vt + (size_t)2 * NKV * S_LEN * HD);     // [2048] f32
  float* sa2  = sa1 + M_ROWS;                                    // [2048] f32
  size_t needed = (size_t)((char*)(sa2 + M_ROWS) - (char*)d_ws);
  if (ws_size < needed) return;
  float* ao  = qkv;    // alias: attention output [2048][4096] f32 (qkv dead)
  f16_t* oq  = xq;     // alias: quantized attn output
  f16_t* woq = wcat;   // alias: quantized Wo

  aquant_kernel<<<M_ROWS, 256, 0, stream>>>(hidden, r_qkv, xq, sa1);
  wquant_kernel<<<4096, 256, 0, stream>>>(Wq, r_qkv, wcat);
  wquant_kernel<<<1024, 256, 0, stream>>>(Wk, r_qkv, wcat + (size_t)4096 * HID);
  wquant_kernel<<<1024, 256, 0, stream>>>(Wv, r_qkv, wcat + (size_t)5120 * HID);
  gemm_bt_f16<<<dim3(NQKV / 128, M_ROWS / 128), 256, 0, stream>>>(xq, wcat, qkv, sa1, M_ROWS, NQKV, HID);
  post_kernel<<<dim3(M_ROWS, NH + 2 * NKV), 128, 0, stream>>>(qkv, cosb, sinb, qnw, knw, Qb, Kb, Vt);
  attn_mfma<<<1024, 256, 0, stream>>>(Qb, Kb, Vt, ao);
  aquant_kernel<<<M_ROWS, 256, 0, stream>>>(ao, r_o, oq, sa2);
  wquant_kernel<<<4096, 256, 0, stream>>>(Wo, r_o, woq);
  gemm_bt_f16<<<dim3(HID / 128, M_ROWS / 128), 256, 0, stream>>>(oq, woq, out, sa2, M_ROWS, HID, HID);
}

// Round 5
// 447.676 us; speedup vs baseline: 13.9640x; 1.0574x over previous
//
#include <hip/hip_runtime.h>
#include <hip/hip_bf16.h>
#include <cstdint>

#define S_LEN 1024
#define HID   4096
#define NH    32
#define NKV   8
#define HD    128
#define NLOW  3968      // HID - SEL
#define M_ROWS 2048     // B*S
#define NQKV  6144      // (NH+2*NKV)*HD

typedef _Float16 f16_t;
typedef _Float16 f16x8 __attribute__((ext_vector_type(8)));
typedef float    f32x4 __attribute__((ext_vector_type(4)));

#define MFMA16(a,b,c) __builtin_amdgcn_mfma_f32_16x16x32_f16(a,b,c,0,0,0)

__device__ inline void gload_lds16(const void* g, void* l) {
  __builtin_amdgcn_global_load_lds(
      (const __attribute__((address_space(1))) void*)g,
      (__attribute__((address_space(3))) void*)l, 16, 0, 0);
}

// ---------- wave reductions (64-wide) ----------
__device__ inline float wred_max(float v){ for(int o=32;o;o>>=1) v=fmaxf(v,__shfl_xor(v,o)); return v; }
__device__ inline float wred_min(float v){ for(int o=32;o;o>>=1) v=fminf(v,__shfl_xor(v,o)); return v; }
__device__ inline float wred_sum(float v){ for(int o=32;o;o>>=1) v+=__shfl_xor(v,o); return v; }

__device__ inline float bsum128(float v, float* red, int t){
  v = wred_sum(v);
  if ((t&63)==0) red[t>>6] = v;
  __syncthreads();
  float r = red[0] + red[1];
  __syncthreads();
  return r;
}
__device__ inline float bmax128(float v, float* red, int t){
  v = wred_max(v);
  if ((t&63)==0) red[t>>6] = v;
  __syncthreads();
  float r = fmaxf(red[0], red[1]);
  __syncthreads();
  return r;
}
__device__ inline float bmin128(float v, float* red, int t){
  v = wred_min(v);
  if ((t&63)==0) red[t>>6] = v;
  __syncthreads();
  float r = fminf(red[0], red[1]);
  __syncthreads();
  return r;
}

// ---------- 1. activation permute + per-row int8 quant ----------
// low cols: store INTEGER q (exact in f16); keep cols: store v/scale.
// GEMM epilogue multiplies output row by scale -> A-side is numerically exact.
__global__ __launch_bounds__(256) void aquant_kernel(const float* __restrict__ X,
                                                     const int* __restrict__ reorder,
                                                     f16_t* __restrict__ out,
                                                     float* __restrict__ sarr)
{
  __shared__ float xs[HID];
  __shared__ float red[256];
  int row = blockIdx.x;
  int t = threadIdx.x;
  const float* xr = X + (size_t)row * HID;
  float amax = 0.f;
  for (int c = t; c < HID; c += 256) {
    float v = xr[reorder[c]];
    xs[c] = v;
    if (c < NLOW) amax = fmaxf(amax, fabsf(v));
  }
  red[t] = amax;
  __syncthreads();
  for (int s = 128; s > 0; s >>= 1) {
    if (t < s) red[t] = fmaxf(red[t], red[t + s]);
    __syncthreads();
  }
  float scale = fmaxf(red[0], 1e-5f) / 127.0f;
  if (t == 0) sarr[row] = scale;
  f16_t* orow = out + (size_t)row * HID;
  for (int c = t; c < HID; c += 256) {
    float v = xs[c];
    if (c < NLOW) {
      float q = fminf(fmaxf(rintf(v / scale), -128.f), 127.f);
      orow[c] = (f16_t)q;            // integer, exact
    } else {
      orow[c] = (f16_t)(v / scale);  // keep col pre-divided by row scale
    }
  }
}

// ---------- 2. weight permute + per-group 4-bit asym quant -> f16 ----------
// One block per row: stage row in LDS (coalesced), gather from LDS.
// Thread t owns permuted cols [16t, 16t+16); 8 lanes = one 128-col group.
__global__ __launch_bounds__(256) void wquant_kernel(const float* __restrict__ W,
                                                     const int* __restrict__ reorder,
                                                     f16_t* __restrict__ out)
{
  __shared__ float xs[HID];
  int row = blockIdx.x;
  int t = threadIdx.x;
  const f32x4* wrow4 = (const f32x4*)(W + (size_t)row * HID);
  f32x4* xs4 = (f32x4*)xs;
  #pragma unroll
  for (int i = 0; i < 4; i++)
    xs4[t + i * 256] = wrow4[t + i * 256];
  __syncthreads();

  int c0 = t * 16;
  float v[16];
  #pragma unroll
  for (int j = 0; j < 16; j++)
    v[j] = xs[reorder[c0 + j]];

  f16_t* orow = out + (size_t)row * HID;
  f16x8 o0, o1;
  if (c0 < NLOW) {
    float mn = v[0], mx = v[0];
    #pragma unroll
    for (int j = 1; j < 16; j++) { mn = fminf(mn, v[j]); mx = fmaxf(mx, v[j]); }
    #pragma unroll
    for (int o = 1; o <= 4; o <<= 1) {
      mn = fminf(mn, __shfl_xor(mn, o));
      mx = fmaxf(mx, __shfl_xor(mx, o));
    }
    float scale = fmaxf(mx - mn, 1e-5f) / 15.0f;
    float base = fminf(fmaxf(rintf(-mn / scale), 0.f), 15.f);
    #pragma unroll
    for (int j = 0; j < 8; j++) {
      o0[j] = (f16_t)((fminf(fmaxf(rintf(v[j] / scale) + base, 0.f), 15.f) - base) * scale);
      o1[j] = (f16_t)((fminf(fmaxf(rintf(v[j + 8] / scale) + base, 0.f), 15.f) - base) * scale);
    }
  } else {
    #pragma unroll
    for (int j = 0; j < 8; j++) { o0[j] = (f16_t)v[j]; o1[j] = (f16_t)v[j + 8]; }
  }
  *(f16x8*)(orow + c0) = o0;
  *(f16x8*)(orow + c0 + 8) = o1;
}

// ---------- 3. deep-pipelined f16 MFMA GEMM ----------
// C[M,N] = rowscale[m] * (A[M,K] * B[N,K]^T), BMx256 tile, BK=64, 512 thr (8 waves 2Mx4N).
// T2: XOR swizzle (16B slot ^= row&7), inverse-swizzled global source, linear gload_lds dest.
// T3/T4: stage tile t+1 at top of tile t, counted s_waitcnt vmcnt(CPW) (never 0 mid-loop).
// T5: setprio around MFMA cluster.
template<int BM_, typename OT>
__global__ __launch_bounds__(512, 2) void gemm_big(const f16_t* __restrict__ A,
                                                   const f16_t* __restrict__ Bm,
                                                   OT* __restrict__ C,
                                                   const float* __restrict__ rowscale,
                                                   int N, int K)
{
  constexpr int MREP = BM_ / 32;   // per-wave 16-row fragments (8 or 4)
  constexpr int ACH  = BM_ / 8;    // A chunks (8 rows each) per K-tile
  constexpr int NCH  = ACH + 32;   // + B chunks
  constexpr int CPW  = NCH / 8;    // gload_lds per wave per K-tile (8 or 6)
  __shared__ f16_t As[2][BM_ * 64];
  __shared__ f16_t Bs[2][256 * 64];

  int tid = threadIdx.x;
  int w = tid >> 6, lane = tid & 63;
  int g = lane >> 4, l15 = lane & 15;
  int lrow = lane >> 3, lslot = lane & 7;
  int wm = w >> 2, wn = w & 3;
  int gm0 = blockIdx.y * BM_, gn0 = blockIdx.x * 256;
  int NT = K >> 6;

  f32x4 zf = {0.f, 0.f, 0.f, 0.f};
  f32x4 acc[MREP][4];
  #pragma unroll
  for (int m = 0; m < MREP; m++)
    #pragma unroll
    for (int n = 0; n < 4; n++) acc[m][n] = zf;

  auto STAGE = [&](int t, int s) {
    #pragma unroll
    for (int i = 0; i < CPW; i++) {
      int ch = w + 8 * i;                       // wave-uniform
      if (ch < ACH) {
        int r = ch * 8 + lrow;
        gload_lds16(A + (size_t)(gm0 + r) * K + t * 64 + (lslot ^ (r & 7)) * 8,
                    &As[s][ch * 512]);
      } else {
        int r = (ch - ACH) * 8 + lrow;
        gload_lds16(Bm + (size_t)(gn0 + r) * K + t * 64 + (lslot ^ (r & 7)) * 8,
                    &Bs[s][(ch - ACH) * 512]);
      }
    }
  };

  STAGE(0, 0);
  for (int t = 0; t < NT; t++) {
    int cur = t & 1;
    if (t + 1 < NT) {
      STAGE(t + 1, cur ^ 1);
      if constexpr (CPW == 8) asm volatile("s_waitcnt vmcnt(8)" ::: "memory");
      else                    asm volatile("s_waitcnt vmcnt(6)" ::: "memory");
    } else {
      asm volatile("s_waitcnt vmcnt(0)" ::: "memory");
    }
    __builtin_amdgcn_s_barrier();               // buf[cur] staged & visible
    asm volatile("" ::: "memory");

    f16x8 bfr[4][2];
    #pragma unroll
    for (int n = 0; n < 4; n++) {
      int r = wn * 64 + n * 16 + l15;
      #pragma unroll
      for (int kk = 0; kk < 2; kk++)
        bfr[n][kk] = *(const f16x8*)(&Bs[cur][r * 64 + (((kk * 4 + g) ^ (r & 7)) * 8)]);
    }
    __builtin_amdgcn_s_setprio(1);
    #pragma unroll
    for (int m = 0; m < MREP; m++) {
      int r = wm * (BM_ / 2) + m * 16 + l15;
      f16x8 a0 = *(const f16x8*)(&As[cur][r * 64 + ((g ^ (r & 7)) * 8)]);
      f16x8 a1 = *(const f16x8*)(&As[cur][r * 64 + (((4 + g) ^ (r & 7)) * 8)]);
      #pragma unroll
      for (int n = 0; n < 4; n++) {
        acc[m][n] = MFMA16(a0, bfr[n][0], acc[m][n]);
        acc[m][n] = MFMA16(a1, bfr[n][1], acc[m][n]);
      }
    }
    __builtin_amdgcn_s_setprio(0);
    asm volatile("" ::: "memory");
    __builtin_amdgcn_s_barrier();               // all reads of buf[cur] done
  }

  #pragma unroll
  for (int m = 0; m < MREP; m++)
    #pragma unroll
    for (int j = 0; j < 4; j++) {
      int grow = gm0 + wm * (BM_ / 2) + m * 16 + g * 4 + j;
      float sc = rowscale[grow];
      #pragma unroll
      for (int n = 0; n < 4; n++) {
        int gcol = gn0 + wn * 64 + n * 16 + l15;
        C[(size_t)grow * N + gcol] = (OT)(acc[m][n][j] * sc);
      }
    }
}

// ---------- 4. post: RMSNorm / kv 4-bit quant / RoPE -> f16 Q,K,V^T ----------
__global__ __launch_bounds__(128) void post_kernel(const f16_t* __restrict__ qkv,
                                                   const float* __restrict__ cosb,
                                                   const float* __restrict__ sinb,
                                                   const float* __restrict__ qnw,
                                                   const float* __restrict__ knw,
                                                   f16_t* __restrict__ Q,
                                                   f16_t* __restrict__ K,
                                                   f16_t* __restrict__ Vt)
{
  int m = blockIdx.x;      // b*S + s
  int slot = blockIdx.y;
  int d = threadIdx.x;
  int b = m >> 10, s = m & 1023;
  __shared__ float buf[128];
  __shared__ float red[2];

  float cv = cosb[(size_t)m * HD + d];
  float sv = sinb[(size_t)m * HD + d];

  if (slot < NH) {                 // q: norm -> rope -> *1/sqrt(HD)
    int h = slot;
    float x = (float)qkv[(size_t)m * NQKV + h * HD + d];
    float ss = bsum128(x * x, red, d);
    float xn = x * (1.0f / sqrtf(ss / 128.0f + 1e-6f)) * qnw[d];
    buf[d] = xn;
    __syncthreads();
    float rot = (d < 64) ? -buf[d + 64] : buf[d - 64];
    float o = (xn * cv + rot * sv) * 0.08838834764831845f;
    Q[(((size_t)(b * NH + h)) * S_LEN + s) * HD + d] = (f16_t)o;
  } else if (slot < NH + NKV) {    // k: norm -> quant -> rope
    int h = slot - NH;
    float x = (float)qkv[(size_t)m * NQKV + NH * HD + h * HD + d];
    float ss = bsum128(x * x, red, d);
    float xn = x * (1.0f / sqrtf(ss / 128.0f + 1e-6f)) * knw[d];
    float mn = bmin128(xn, red, d);
    float mx = bmax128(xn, red, d);
    float scale = fmaxf(mx - mn, 1e-5f) / 15.0f;
    float base = fminf(fmaxf(rintf(-mn / scale), 0.f), 15.f);
    float xq = (fminf(fmaxf(rintf(xn / scale) + base, 0.f), 15.f) - base) * scale;
    buf[d] = xq;
    __syncthreads();
    float rot = (d < 64) ? -buf[d + 64] : buf[d - 64];
    float o = xq * cv + rot * sv;
    K[(((size_t)(b * NKV + h)) * S_LEN + s) * HD + d] = (f16_t)o;
  } else {                         // v: quant only, store transposed [HD][S]
    int h = slot - NH - NKV;
    float x = (float)qkv[(size_t)m * NQKV + (NH + NKV) * HD + h * HD + d];
    float mn = bmin128(x, red, d);
    float mx = bmax128(x, red, d);
    float scale = fmaxf(mx - mn, 1e-5f) / 15.0f;
    float base = fminf(fmaxf(rintf(-mn / scale), 0.f), 15.f);
    float xq = (fminf(fmaxf(rintf(x / scale) + base, 0.f), 15.f) - base) * scale;
    Vt[((size_t)(b * NKV + h) * HD + d) * S_LEN + s] = (f16_t)xq;
  }
}

// ---------- 5. flash attention, f16 MFMA ----------
// block: 256 thr (4 waves), 64 q-rows (16/wave), KBLK=64.
// K LDS [64][128] swz, V^T LDS [128][64] swz, P per-wave [16][64] swz.
__global__ __launch_bounds__(256) void attn_mfma(const f16_t* __restrict__ Q,
                                                 const f16_t* __restrict__ Kg,
                                                 const f16_t* __restrict__ Vg,
                                                 float* __restrict__ O)
{
  __shared__ f16_t Ks[64 * 128];
  __shared__ f16_t Vs[128 * 64];
  __shared__ f16_t Ps[4 * 16 * 64];
  int tid = threadIdx.x;
  int w = tid >> 6, lane = tid & 63;
  int g = lane >> 4, l15 = lane & 15;
  int flat = blockIdx.x;              // qb in high bits -> mixed tile counts per CU
  int h = flat & 31, b = (flat >> 5) & 1, qb = flat >> 6;
  int kvh = h >> 2;
  int q0 = qb * 64;

  const f16_t* Qp = Q + (size_t)(b * NH + h) * S_LEN * HD;
  const f16_t* Kp = Kg + (size_t)(b * NKV + kvh) * S_LEN * HD;
  const f16_t* Vp = Vg + (size_t)(b * NKV + kvh) * HD * S_LEN;

  int qrow = q0 + w * 16 + l15;
  f16x8 qf[4];
  #pragma unroll
  for (int c = 0; c < 4; c++)
    qf[c] = *(const f16x8*)(Qp + (size_t)qrow * HD + c * 32 + g * 8);

  f32x4 zf = {0.f, 0.f, 0.f, 0.f};
  f32x4 oacc[8];
  #pragma unroll
  for (int nd = 0; nd < 8; nd++) oacc[nd] = zf;
  float mrun[4], lrun[4];
  #pragma unroll
  for (int j = 0; j < 4; j++) { mrun[j] = -INFINITY; lrun[j] = 0.f; }

  f16_t* pw = Ps + w * 1024;
  int ntiles = qb + 1;
  for (int it = 0; it < ntiles; it++) {
    int kt = it * 64;
    // stage K tile: 16 chunks of 1KB (4 rows x 16 slots), src slot pre-swizzled
    #pragma unroll
    for (int i = 0; i < 4; i++) {
      int c = w + 4 * i;
      int row = c * 4 + g;
      int ss = l15 ^ (row & 7);
      gload_lds16(Kp + (size_t)(kt + row) * HD + ss * 8, Ks + c * 512);
    }
    // stage V^T tile: 16 chunks (8 rows x 8 slots)
    #pragma unroll
    for (int i = 0; i < 4; i++) {
      int c = w + 4 * i;
      int row = c * 8 + (lane >> 3);
      int ss = (lane & 7) ^ (row & 7);
      gload_lds16(Vp + (size_t)row * S_LEN + kt + ss * 8, Vs + c * 512);
    }
    __syncthreads();

    // QK^T: S[16q][64k], rows(reg)=q, cols(lane&15)=k
    f32x4 sv[4];
    #pragma unroll
    for (int nk = 0; nk < 4; nk++) sv[nk] = zf;
    #pragma unroll
    for (int nk = 0; nk < 4; nk++) {
      int krow = nk * 16 + l15;
      #pragma unroll
      for (int c = 0; c < 4; c++) {
        f16x8 kf = *(const f16x8*)(Ks + krow * 128 + ((c * 4 + g) ^ (krow & 7)) * 8);
        sv[nk] = MFMA16(qf[c], kf, sv[nk]);
      }
    }
    // causal mask
    #pragma unroll
    for (int nk = 0; nk < 4; nk++) {
      int kcol = kt + nk * 16 + l15;
      #pragma unroll
      for (int j = 0; j < 4; j++) {
        int qr = q0 + w * 16 + g * 4 + j;
        if (kcol > qr) sv[nk][j] = -1e30f;
      }
    }
    // online softmax (row stats live in the 16 lanes of each lane-group)
    float alpha[4];
    #pragma unroll
    for (int j = 0; j < 4; j++) {
      float mr = fmaxf(fmaxf(sv[0][j], sv[1][j]), fmaxf(sv[2][j], sv[3][j]));
      mr = fmaxf(mr, __shfl_xor(mr, 1));
      mr = fmaxf(mr, __shfl_xor(mr, 2));
      mr = fmaxf(mr, __shfl_xor(mr, 4));
      mr = fmaxf(mr, __shfl_xor(mr, 8));
      float mnew = fmaxf(mrun[j], mr);
      alpha[j] = __expf(mrun[j] - mnew);
      float lt = 0.f;
      #pragma unroll
      for (int nk = 0; nk < 4; nk++) {
        float p = __expf(sv[nk][j] - mnew);
        sv[nk][j] = p;
        lt += p;
      }
      lt += __shfl_xor(lt, 1);
      lt += __shfl_xor(lt, 2);
      lt += __shfl_xor(lt, 4);
      lt += __shfl_xor(lt, 8);
      lrun[j] = lrun[j] * alpha[j] + lt;
      mrun[j] = mnew;
    }
    // write P (f16, swizzled rows of 64 elems)
    #pragma unroll
    for (int j = 0; j < 4; j++) {
      int ql = g * 4 + j;
      #pragma unroll
      for (int nk = 0; nk < 4; nk++) {
        int kl = nk * 16 + l15;
        int ss = (kl >> 3) ^ (ql & 7);
        pw[ql * 64 + ss * 8 + (kl & 7)] = (f16_t)sv[nk][j];
      }
    }
    // rescale O
    #pragma unroll
    for (int nd = 0; nd < 8; nd++)
      #pragma unroll
      for (int j = 0; j < 4; j++) oacc[nd][j] *= alpha[j];
    // PV: O[16q][128d] += P[16q][64k] * V[64k][128d]
    #pragma unroll
    for (int kc = 0; kc < 2; kc++) {
      f16x8 pf = *(const f16x8*)(pw + l15 * 64 + ((kc * 4 + g) ^ (l15 & 7)) * 8);
      #pragma unroll
      for (int nd = 0; nd < 8; nd++) {
        int d = nd * 16 + l15;
        f16x8 vf = *(const f16x8*)(Vs + d * 64 + ((kc * 4 + g) ^ (d & 7)) * 8);
        oacc[nd] = MFMA16(pf, vf, oacc[nd]);
      }
    }
    __syncthreads();
  }
  // epilogue: write (B,S,NH*HD) f32
  #pragma unroll
  for (int j = 0; j < 4; j++) {
    float invl = 1.0f / lrun[j];
    float* orow = O + ((size_t)(b * S_LEN) + q0 + w * 16 + g * 4 + j) * (NH * HD) + h * HD + l15;
    #pragma unroll
    for (int nd = 0; nd < 8; nd++) orow[nd * 16] = oacc[nd][j] * invl;
  }
}

// ---------- launcher ----------
extern "C" void kernel_launch(void* const* d_in, const int* in_sizes, int n_in,
                              void* d_out, int out_size, void* d_ws, size_t ws_size,
                              hipStream_t stream) {
  const float* hidden = (const float*)d_in[0];
  const float* cosb   = (const float*)d_in[1];
  const float* sinb   = (const float*)d_in[2];
  const float* Wq     = (const float*)d_in[3];
  const float* Wk     = (const float*)d_in[4];
  const float* Wv     = (const float*)d_in[5];
  const float* Wo     = (const float*)d_in[6];
  const float* qnw    = (const float*)d_in[7];
  const float* knw    = (const float*)d_in[8];
  const int*   r_qkv  = (const int*)d_in[9];
  const int*   r_o    = (const int*)d_in[10];
  float* out = (float*)d_out;

  f16_t* xq   = (f16_t*)d_ws;                                    // [2048][4096] f16
  f16_t* wcat = xq + (size_t)M_ROWS * HID;                       // [6144][4096] f16
  f16_t* qkv  = wcat + (size_t)NQKV * HID;                       // [2048][6144] f16
  f16_t* Qb   = qkv + (size_t)M_ROWS * NQKV;                     // [2*32*1024][128] f16
  f16_t* Kb   = Qb + (size_t)2 * NH * S_LEN * HD;                // [2*8*1024][128] f16
  f16_t* Vt   = Kb + (size_t)2 * NKV * S_LEN * HD;               // [2*8][128][1024] f16
  float* sa1  = (float*)(Vt + (size_t)2 * NKV * S_LEN * HD);     // [2048] f32
  float* sa2  = sa1 + M_ROWS;                                    // [2048] f32
  float* ao   = sa2 + M_ROWS;                                    // [2048][4096] f32
  size_t needed = (size_t)((char*)(ao + (size_t)M_ROWS * HID) - (char*)d_ws);
  if (ws_size < needed) return;
  f16_t* oq  = xq;     // alias: quantized attn output (xq dead after QKV GEMM)
  f16_t* woq = wcat;   // alias: quantized Wo (wcat dead after QKV GEMM)

  aquant_kernel<<<M_ROWS, 256, 0, stream>>>(hidden, r_qkv, xq, sa1);
  wquant_kernel<<<4096, 256, 0, stream>>>(Wq, r_qkv, wcat);
  wquant_kernel<<<1024, 256, 0, stream>>>(Wk, r_qkv, wcat + (size_t)4096 * HID);
  wquant_kernel<<<1024, 256, 0, stream>>>(Wv, r_qkv, wcat + (size_t)5120 * HID);
  gemm_big<256, f16_t><<<dim3(NQKV / 256, M_ROWS / 256), 512, 0, stream>>>(xq, wcat, qkv, sa1, NQKV, HID);
  post_kernel<<<dim3(M_ROWS, NH + 2 * NKV), 128, 0, stream>>>(qkv, cosb, sinb, qnw, knw, Qb, Kb, Vt);
  attn_mfma<<<1024, 256, 0, stream>>>(Qb, Kb, Vt, ao);
  aquant_kernel<<<M_ROWS, 256, 0, stream>>>(ao, r_o, oq, sa2);
  wquant_kernel<<<4096, 256, 0, stream>>>(Wo, r_o, woq);
  gemm_big<128, float><<<dim3(HID / 256, M_ROWS / 128), 512, 0, stream>>>(oq, woq, out, sa2, HID, HID);
}